// Round 1
// baseline (407.672 us; speedup 1.0000x reference)
//
#include <hip/hip_runtime.h>
#include <stdint.h>

#define K_TOT 4096
#define N_TOT 11008
#define M_TOT 256
#define BM 128
#define BN 64
#define WST 72   // padded LDS row stride in ushorts (144B = 16B-aligned, 2-way-free banks)

using bf16x8 = __attribute__((ext_vector_type(8))) short;
using f32x4  = __attribute__((ext_vector_type(4))) float;

// lgkmcnt-only barrier: LDS visibility without draining the vmem (W-prefetch) queue.
// __syncthreads() would emit s_waitcnt vmcnt(0) and kill the global prefetch pipeline.
#define BAR() do {                                          \
    asm volatile("s_waitcnt lgkmcnt(0)" ::: "memory");      \
    __builtin_amdgcn_s_barrier();                           \
    asm volatile("" ::: "memory");                          \
} while (0)

// ---------- prep: fp32 -> bf16 (RNE) for the activation ----------
__global__ void cvt_a_bf16(const float* __restrict__ in, uint32_t* __restrict__ out) {
    int i = blockIdx.x * blockDim.x + threadIdx.x;       // one float4 per thread
    const float4 v = ((const float4*)in)[i];
    uint32_t a = __float_as_uint(v.x), b = __float_as_uint(v.y),
             c = __float_as_uint(v.z), d = __float_as_uint(v.w);
    a += 0x7FFFu + ((a >> 16) & 1u);
    b += 0x7FFFu + ((b >> 16) & 1u);
    c += 0x7FFFu + ((c >> 16) & 1u);
    d += 0x7FFFu + ((d >> 16) & 1u);
    uint2 o;
    o.x = (a >> 16) | (b & 0xFFFF0000u);
    o.y = (c >> 16) | (d & 0xFFFF0000u);
    ((uint2*)out)[i] = o;
}

__device__ __forceinline__ uint32_t pack_hi16(uint32_t u0, uint32_t u1) {
#if __has_builtin(__builtin_amdgcn_perm)
    return __builtin_amdgcn_perm(u1, u0, 0x07060302u);   // bytes {u0.b2,u0.b3,u1.b2,u1.b3}
#else
    return (u0 >> 16) | (u1 & 0xFFFF0000u);
#endif
}

__device__ __forceinline__ float clamp3(float q, float lo, float hi) {
#if __has_builtin(__builtin_amdgcn_fmed3f)
    return __builtin_amdgcn_fmed3f(q, lo, hi);           // lo<=hi always (0<=zp<=15)
#else
    return fminf(fmaxf(q, lo), hi);
#endif
}

// ---------- dequant 16 fp32 -> 16 bf16 packed into 8 dwords ----------
// clamp(round(w*rs)+zp,0,15)-zp  ==  med3(rint(w*rs), -zp, 15-zp)   (exact: small ints in fp32)
__device__ __forceinline__ void dequant16(const f32x4* w, float rs, float lo, float hi,
                                          float sc, uint32_t o[8]) {
    uint32_t u[16];
#pragma unroll
    for (int j = 0; j < 4; ++j) {
#pragma unroll
        for (int e = 0; e < 4; ++e) {
            float q  = rintf(w[j][e] * rs);              // round-half-even, matches jnp.round
            q        = clamp3(q, lo, hi);
            float dq = q * sc;
            uint32_t b = __float_as_uint(dq);
            u[4 * j + e] = b + 0x7FFFu + ((b >> 16) & 1u);   // bf16 RNE in high 16 bits
        }
    }
#pragma unroll
    for (int i = 0; i < 8; ++i) o[i] = pack_hi16(u[2 * i], u[2 * i + 1]);
}

// ---------- fused dequant + GEMM over a K-chunk, writes fp32 partials ----------
__global__ __launch_bounds__(256, 3)
void wql_gemm(const uint16_t* __restrict__ A,      // bf16 [256][4096]
              const float* __restrict__ W,         // fp32 [11008][4096]
              const float* __restrict__ scale,
              const float* __restrict__ zero,
              float* __restrict__ P,               // fp32 [KS][256][11008]
              int kloc) {                          // K-chunk length (multiple of 256)
    __shared__ uint16_t sW[2][BN][WST];            // 18.4 KB, double-buffered W tile (bf16)

    const int tid  = threadIdx.x;
    const int lane = tid & 63;
    const int wv   = tid >> 6;
    const int wm   = (wv & 1) * 64;
    const int wn   = (wv >> 1) * 32;
    const int m0   = blockIdx.x * BM;
    const int n0   = blockIdx.y * BN;
    const int k0   = blockIdx.z * kloc;
    const int nkt  = kloc >> 6;                    // 64-K steps (multiple of 4)

    // --- W staging role: thread owns one (row, 16-float k-segment) slot ---
    const int nloc = tid >> 2;                     // 0..63
    const int kseg = tid & 3;                      // 0..3
    const int wrow = n0 + nloc;
    const float* Wp = W + (size_t)wrow * K_TOT + k0 + kseg * 16;
    const float sc = scale[wrow];
    const float zp = zero[wrow];
    const float rs = 1.0f / sc;
    const float lo = -zp, hi = 15.0f - zp;

    // --- A fragment base pointers (direct-from-global, L2/LLC-resident) ---
    const uint16_t* Ap[4];
#pragma unroll
    for (int mi = 0; mi < 4; ++mi)
        Ap[mi] = A + (size_t)(m0 + wm + mi * 16 + (lane & 15)) * K_TOT + k0 + (lane >> 4) * 8;

    f32x4 acc[4][2];
#pragma unroll
    for (int mi = 0; mi < 4; ++mi)
#pragma unroll
        for (int ni = 0; ni < 2; ++ni)
            acc[mi][ni] = (f32x4){0.f, 0.f, 0.f, 0.f};

    // --- 4-deep register bank pipeline: bank[s&3] holds W-column-block s ---
    f32x4 bank[4][4];

    // prologue: issue loads for steps 0,1,2 back-to-back; dequant step 0 into sW[0]
#pragma unroll
    for (int s = 0; s < 3; ++s) {
        const f32x4* p = (const f32x4*)(Wp + (size_t)s * 64);
#pragma unroll
        for (int j = 0; j < 4; ++j) bank[s][j] = __builtin_nontemporal_load(p + j);
    }
    {
        uint32_t o[8];
        dequant16(bank[0], rs, lo, hi, sc, o);
        uint16_t* d = &sW[0][nloc][kseg * 16];
        ((uint4*)d)[0] = make_uint4(o[0], o[1], o[2], o[3]);
        ((uint4*)d)[1] = make_uint4(o[4], o[5], o[6], o[7]);
    }
    BAR();

    for (int st = 0; st < nkt; st += 4) {
#pragma unroll
        for (int u = 0; u < 4; ++u) {              // all bank/sW indices compile-time
            const int step = st + u;

            // W prefetch: issue loads for step+3 (consumed 2.5 steps from now)
            if (step + 3 < nkt) {
                const f32x4* p = (const f32x4*)(Wp + (size_t)(step + 3) * 64);
#pragma unroll
                for (int j = 0; j < 4; ++j)
                    bank[(u + 3) & 3][j] = __builtin_nontemporal_load(p + j);
            }

            // compute current step from sW[u&1]
            {
                const int koff = step * 64;
#pragma unroll
                for (int s = 0; s < 2; ++s) {
                    bf16x8 a[4], b[2];
#pragma unroll
                    for (int mi = 0; mi < 4; ++mi)
                        a[mi] = *(const bf16x8*)(Ap[mi] + koff + s * 32);
#pragma unroll
                    for (int ni = 0; ni < 2; ++ni)
                        b[ni] = *(const bf16x8*)&sW[u & 1][wn + ni * 16 + (lane & 15)]
                                                  [s * 32 + (lane >> 4) * 8];
#pragma unroll
                    for (int mi = 0; mi < 4; ++mi)
#pragma unroll
                        for (int ni = 0; ni < 2; ++ni)
                            acc[mi][ni] = __builtin_amdgcn_mfma_f32_16x16x32_bf16(
                                a[mi], b[ni], acc[mi][ni], 0, 0, 0);
                }
            }

            // dequant step+1 into the other LDS half
            if (step + 1 < nkt) {
                uint32_t o[8];
                dequant16(bank[(u + 1) & 3], rs, lo, hi, sc, o);
                uint16_t* d = &sW[(u + 1) & 1][nloc][kseg * 16];
                ((uint4*)d)[0] = make_uint4(o[0], o[1], o[2], o[3]);
                ((uint4*)d)[1] = make_uint4(o[4], o[5], o[6], o[7]);
            }

            BAR();
        }
    }

    // --- epilogue: store fp32 partial (no bias here), streaming stores ---
    float* Pb = P + (size_t)blockIdx.z * M_TOT * N_TOT;
    const int colbase = n0 + wn + (lane & 15);
    const int rbase = m0 + wm + ((lane >> 4) << 2);
#pragma unroll
    for (int mi = 0; mi < 4; ++mi) {
#pragma unroll
        for (int ni = 0; ni < 2; ++ni) {
            const int col = colbase + ni * 16;
#pragma unroll
            for (int r = 0; r < 4; ++r) {
                const int row = rbase + mi * 16 + r;
                __builtin_nontemporal_store(acc[mi][ni][r], &Pb[(size_t)row * N_TOT + col]);
            }
        }
    }
}

// ---------- reduce KS partial slices + bias -> out (float4 per thread) ----------
__global__ void reduce_bias(const float* __restrict__ P, const float* __restrict__ bias,
                            float* __restrict__ out, int ks) {
    const int i4 = blockIdx.x * blockDim.x + threadIdx.x;   // float4 index
    const size_t tot4 = (size_t)M_TOT * N_TOT / 4;
    const int col = (int)(((size_t)i4 * 4) % N_TOT);        // rows are multiple-of-4 long
    f32x4 acc = __builtin_nontemporal_load((const f32x4*)P + i4);
    for (int s = 1; s < ks; ++s) {
        const f32x4 v = __builtin_nontemporal_load((const f32x4*)P + (size_t)s * tot4 + i4);
        acc += v;
    }
    const float4 b = *(const float4*)(bias + col);
    acc[0] += b.x; acc[1] += b.y; acc[2] += b.z; acc[3] += b.w;
    *((f32x4*)out + i4) = acc;
}

extern "C" void kernel_launch(void* const* d_in, const int* in_sizes, int n_in,
                              void* d_out, int out_size, void* d_ws, size_t ws_size,
                              hipStream_t stream) {
    const float* inp    = (const float*)d_in[0];
    const float* weight = (const float*)d_in[1];
    const float* bias   = (const float*)d_in[2];
    const float* scale  = (const float*)d_in[3];
    const float* zero   = (const float*)d_in[4];
    // d_in[5] = maxq scalar; fixed at 15 by the reference, hardcoded in dequant16.

    const size_t A_BYTES = (size_t)M_TOT * K_TOT * 2;       // 2 MB bf16 activation
    const size_t SLICE   = (size_t)M_TOT * N_TOT * 4;       // 11 MB fp32 partial

    uint32_t* Abf = (uint32_t*)d_ws;
    float* partial;
    int KS;
    if (ws_size >= A_BYTES + 4 * SLICE) { KS = 4; partial = (float*)((char*)d_ws + A_BYTES); }
    else if (ws_size >= A_BYTES + 2 * SLICE) { KS = 2; partial = (float*)((char*)d_ws + A_BYTES); }
    else { KS = 1; partial = (float*)d_out; }               // in-place: reduce adds bias only

    cvt_a_bf16<<<dim3((M_TOT * K_TOT / 4) / 256), dim3(256), 0, stream>>>(inp, Abf);

    dim3 grid(M_TOT / BM, N_TOT / BN, KS);                  // (2, 172, KS)
    wql_gemm<<<grid, dim3(256), 0, stream>>>((const uint16_t*)Abf, weight, scale, zero,
                                             partial, K_TOT / KS);

    reduce_bias<<<dim3((M_TOT * N_TOT / 4) / 256), dim3(256), 0, stream>>>(
        partial, bias, (float*)d_out, KS);
}